// Round 14
// baseline (93.482 us; speedup 1.0000x reference)
//
#include <hip/hip_runtime.h>
#include <stdint.h>

#define BB 4
#define CCH 64
#define LLEN 4096
#define QS2 0.18033688011112042f   // 0.125 * log2(e)
#define TQ 64
#define TK 64
#define NCHUNK 8
#define TPC 8
#define NTB 256
// emit geometry: 128-lq blocks, 8 waves, 4 chunks of 1024 lk
#define TQE 128
#define NTE 512
#define NCHE 4
#define TPE 16

typedef __bf16 bf16;
typedef bf16 bf16x4 __attribute__((ext_vector_type(4)));
typedef bf16 bf16x8 __attribute__((ext_vector_type(8)));
typedef float f32x4 __attribute__((ext_vector_type(4)));

#define EXP2F(x) __builtin_amdgcn_exp2f(x)
#define LOG2F(x) __builtin_amdgcn_logf(x)

// swizzled element index into a [rows][64 cols] bf16 tile (128B rows)
__device__ __forceinline__ int swz(int row, int col) {
    return row * 64 + (col ^ ((row & 7) << 3));
}

__device__ __forceinline__ void g2l16(const void* g, void* l) {
    __builtin_amdgcn_global_load_lds(
        (const __attribute__((address_space(1))) void*)g,
        (__attribute__((address_space(3))) void*)l, 16, 0, 0);
}

#define WAITVM0 asm volatile("s_waitcnt vmcnt(0)" ::: "memory")
#define WAITVM16 asm volatile("s_waitcnt vmcnt(16)" ::: "memory")
#define WAITLGKM0 asm volatile("s_waitcnt lgkmcnt(0)" ::: "memory")
#define BAR() __builtin_amdgcn_s_barrier()
#define PRIO(n) __builtin_amdgcn_s_setprio(n)

// copy contiguous region global->LDS: 2 g2l16 per wave (4 waves: 8KB, 8 waves: 16KB)
__device__ __forceinline__ void stage_rows(const bf16* src, bf16* dst, int w, int l) {
#pragma unroll
    for (int i = 0; i < 2; ++i) {
        int ci = w * 2 + i;
        g2l16(src + ci * 512 + l * 8, dst + ci * 512);
    }
}
// copy one 8KB contiguous tile with 8 waves (1 g2l16 per wave)
__device__ __forceinline__ void stage_tile8(const bf16* src, bf16* dst, int w, int l) {
    g2l16(src + w * 512 + l * 8, dst + w * 512);
}

// ---------------- prep (merged): Q,K transpose+swizzle | V pack | mask ----------------
__global__ __launch_bounds__(NTB) void prep_all(
    const float* __restrict__ qg, const float* __restrict__ kg,
    const float* __restrict__ vg, const float* __restrict__ mg,
    bf16* __restrict__ qT, bf16* __restrict__ kT,
    bf16* __restrict__ vF, float* __restrict__ wS, float* __restrict__ wE)
{
    const int tid = threadIdx.x;
    if (blockIdx.x < 512) {
        __shared__ float t[64][65];
        const int isK = blockIdx.x >> 8;
        const int idx = blockIdx.x & 255;
        const int b = idx >> 6;
        const int lt = idx & 63;
        const float* src = (isK ? kg : qg) + (size_t)b * CCH * LLEN + lt * 64;
        bf16* dst = (isK ? kT : qT) + ((size_t)b * LLEN + lt * 64) * 64;

        int c = tid >> 2, x0 = (tid & 3) * 16;
#pragma unroll
        for (int j = 0; j < 4; ++j) {
            float4 f = *(const float4*)&src[(size_t)c * LLEN + x0 + j * 4];
            t[c][x0 + j * 4 + 0] = f.x;
            t[c][x0 + j * 4 + 1] = f.y;
            t[c][x0 + j * 4 + 2] = f.z;
            t[c][x0 + j * 4 + 3] = f.w;
        }
        __syncthreads();
        int lk = tid >> 2;
        int g0 = (tid & 3) * 2;
#pragma unroll
        for (int gi = 0; gi < 2; ++gi) {
            int gg = g0 + gi;
            bf16x8 v;
#pragma unroll
            for (int j = 0; j < 8; ++j) v[j] = (bf16)t[gg * 8 + j][lk];
            *(bf16x8*)&dst[lk * 64 + ((gg ^ (lk & 7)) * 8)] = v;
        }
    } else if (blockIdx.x < 768) {
        // V -> PV-fragment-packed: unit ((b*64+tile)*8 + s*4 + mt)*64 + 16*g + cl
        const int row = blockIdx.x - 512;  // b*64 + c
        const int b = row >> 6;
        const int c = row & 63;
        const int mt = c >> 4, cl = c & 15;
        const size_t base = (size_t)row * LLEN;
        const int x0 = tid * 16;
        const int tile = x0 >> 6;
        float f[16];
#pragma unroll
        for (int j = 0; j < 4; ++j) {
            float4 v4 = *(const float4*)&vg[base + x0 + j * 4];
            f[j * 4 + 0] = v4.x; f[j * 4 + 1] = v4.y;
            f[j * 4 + 2] = v4.z; f[j * 4 + 3] = v4.w;
        }
        bf16* vFb = vF + (size_t)(b * 64 + tile) * 4096;
#pragma unroll
        for (int k2 = 0; k2 < 4; ++k2) {
            int rem = (x0 & 63) + 4 * k2;
            int s = rem >> 5, hl = (rem >> 4) & 1, g = (rem >> 2) & 3;
            bf16x4 hv = {(bf16)f[4 * k2 + 0], (bf16)f[4 * k2 + 1],
                         (bf16)f[4 * k2 + 2], (bf16)f[4 * k2 + 3]};
            *(bf16x4*)&vFb[(size_t)(((s * 4 + mt) * 64 + 16 * g + cl) * 8 + hl * 4)] = hv;
        }
    } else {
        const int b = blockIdx.x - 768;
        int x0 = tid * 16;
#pragma unroll
        for (int j = 0; j < 16; ++j) {
            float m = mg[(size_t)b * LLEN + x0 + j];
            float w = m + 1e-6f;
            wS[(size_t)b * LLEN + x0 + j] = LOG2F(w);       // log2(mask + 1e-6)
            wE[(size_t)b * LLEN + x0 + j] = LOG2F(w * m);   // + log2(mask); m=0 -> -inf
        }
    }
}

// ---------------- stats: lk-split waves; per-chunk row sums; optional zero out ----------------
__global__ __launch_bounds__(NTB) void attn_stats(
    const bf16* __restrict__ qT, const bf16* __restrict__ kT,
    const float* __restrict__ wS, float* __restrict__ sums,
    float* __restrict__ outp, int zero_out)
{
    __shared__ __align__(16) bf16 kbuf[2][TK * CCH];
    __shared__ __align__(16) float wbuf[2][TK];
    __shared__ float red[4][TQ];

    const int tid = threadIdx.x;
    const int l = tid & 63;
    const int w = tid >> 6;          // wave owns lk slice [16w, 16w+16)
    const int g = l >> 4;
    const int cl = l & 15;

    const int idx = blockIdx.x;
    const int chunk = idx & 7;
    const int lqt = (idx >> 3) & 63;
    const int b = idx >> 9;
    const int lq0 = lqt * TQ;
    const size_t bL = (size_t)b * LLEN;

    // zero out region only in atomic-fallback mode
    if (zero_out) {
        size_t o = ((size_t)idx * NTB + tid) * 2;
        *(float2*)&outp[o] = make_float2(0.f, 0.f);
    }

    // prologue: Q -> kbuf[1] (transient), K(tile0) -> kbuf[0], wS0 -> wbuf[0]
    stage_rows(qT + (bL + lq0) * 64, kbuf[1], w, l);
    stage_rows(kT + (bL + chunk * 512) * 64, kbuf[0], w, l);
    if (w == 0 && l < 16) g2l16(wS + bL + chunk * 512 + l * 4, wbuf[0]);
    WAITVM0;
    BAR();
    // Q fragments for ALL 4 strips (held in registers; kbuf[1] is then reusable)
    bf16x8 qf[4][2];
#pragma unroll
    for (int strip = 0; strip < 4; ++strip) {
        qf[strip][0] = *(const bf16x8*)&kbuf[1][swz(strip * 16 + cl, 8 * g)];
        qf[strip][1] = *(const bf16x8*)&kbuf[1][swz(strip * 16 + cl, 32 + 8 * g)];
    }
    WAITLGKM0;
    BAR();

    float sacc[4] = {0.f, 0.f, 0.f, 0.f};
#pragma unroll
    for (int it = 0; it < TPC; ++it) {
        const int kcur = it & 1;
        const int lk0 = chunk * 512 + it * 64;

        if (it < TPC - 1) {
            stage_rows(kT + (bL + lk0 + 64) * 64, kbuf[kcur ^ 1], w, l);
            if (w == 0 && l < 16) g2l16(wS + bL + lk0 + 64 + l * 4, wbuf[kcur ^ 1]);
        }

        // A fragments: this wave's own 16-lk slice (only 2 LDS reads/iter)
        bf16x8 kf0 = *(const bf16x8*)&kbuf[kcur][swz(16 * w + cl, 8 * g)];
        bf16x8 kf1 = *(const bf16x8*)&kbuf[kcur][swz(16 * w + cl, 32 + 8 * g)];
        float4 wv = *(const float4*)&wbuf[kcur][16 * w + 4 * g];

        PRIO(1);
#pragma unroll
        for (int strip = 0; strip < 4; ++strip) {
            f32x4 e = (f32x4){0.f, 0.f, 0.f, 0.f};
            e = __builtin_amdgcn_mfma_f32_16x16x32_bf16(kf0, qf[strip][0], e, 0, 0, 0);
            e = __builtin_amdgcn_mfma_f32_16x16x32_bf16(kf1, qf[strip][1], e, 0, 0, 0);
            sacc[strip] += EXP2F(fmaf(e[0], QS2, wv.x));
            sacc[strip] += EXP2F(fmaf(e[1], QS2, wv.y));
            sacc[strip] += EXP2F(fmaf(e[2], QS2, wv.z));
            sacc[strip] += EXP2F(fmaf(e[3], QS2, wv.w));
        }
        PRIO(0);

        if (it < TPC - 1) {
            WAITVM0;
            WAITLGKM0;
            BAR();
        }
    }

    // reduce over g (lanes 16,32 apart hold other lk rows of the slice)
#pragma unroll
    for (int strip = 0; strip < 4; ++strip) {
        sacc[strip] += __shfl_xor(sacc[strip], 16);
        sacc[strip] += __shfl_xor(sacc[strip], 32);
    }
    if (l < 16) {
#pragma unroll
        for (int strip = 0; strip < 4; ++strip) red[w][strip * 16 + l] = sacc[strip];
    }
    __syncthreads();
    if (tid < TQ) {
        float s = red[0][tid] + red[1][tid] + red[2][tid] + red[3][tid];
        sums[(bL + lq0 + tid) * NCHUNK + chunk] = s;
    }
}

// ---------------- emit: 8-wave, 128-lq blocks; QK^T, normalize, attnT, PV ----------------
__global__ __launch_bounds__(NTE, 4) void attn_emit(
    const bf16* __restrict__ qT, const bf16* __restrict__ kT,
    const bf16* __restrict__ vF, const float* __restrict__ wE,
    const float* __restrict__ sums, float* __restrict__ outp,
    float* __restrict__ pout, int use_part,
    float* __restrict__ attnT)
{
    __shared__ __align__(16) bf16 kbuf[2][TK * CCH];   // also Q transient (16KB flat)
    __shared__ __align__(16) bf16 vbuf[2][TK * CCH];
    __shared__ __align__(16) float wbuf[2][TK];

    const int tid = threadIdx.x;
    const int l = tid & 63;
    const int w = tid >> 6;        // 0..7
    const int strip = w * 16;      // lq strip within 128
    const int g = l >> 4;
    const int cl = l & 15;

    const int idx = blockIdx.x;
    const int chunk = idx & (NCHE - 1);
    const int lqt = (idx >> 2) & 31;
    const int b = idx >> 7;
    const int lq0 = lqt * TQE;
    const size_t bL = (size_t)b * LLEN;
    const size_t obase = (size_t)b * CCH * LLEN;
    bf16* kflat = &kbuf[0][0];

    // prologue: Q (16KB) -> kbuf flat
    stage_rows(qT + (bL + lq0) * 64, kflat, w, l);
    float ls2;
    {
        const float4* sp = (const float4*)&sums[(bL + lq0 + strip + cl) * NCHUNK];
        float4 a = sp[0], c4 = sp[1];
        float ssum = ((a.x + a.y) + (a.z + a.w)) + ((c4.x + c4.y) + (c4.z + c4.w));
        ls2 = -LOG2F(ssum);  // p = exp2(e*QS2 + ls2 + l2wE)
    }
    WAITVM0;
    BAR();
    bf16x8 qf0 = *(const bf16x8*)&kflat[swz(strip + cl, 8 * g)];
    bf16x8 qf1 = *(const bf16x8*)&kflat[swz(strip + cl, 32 + 8 * g)];
    WAITLGKM0;
    BAR();

    // stage tile 0
    {
        const int lk0 = chunk * (TPE * TK);
        stage_tile8(kT + (bL + lk0) * 64, kbuf[0], w, l);
        stage_tile8(vF + (size_t)(b * 64 + (lk0 >> 6)) * 4096, vbuf[0], w, l);
        if (w == 0 && l < 16) g2l16(wE + bL + lk0 + l * 4, wbuf[0]);
    }
    WAITVM0;
    BAR();

    f32x4 o4[4];
#pragma unroll
    for (int t = 0; t < 4; ++t) o4[t] = (f32x4){0.f, 0.f, 0.f, 0.f};

#pragma unroll
    for (int it = 0; it < TPE; ++it) {
        const int cur = it & 1;
        const int lk0 = chunk * (TPE * TK) + it * 64;

        if (it < TPE - 1) {
            stage_tile8(kT + (bL + lk0 + 64) * 64, kbuf[cur ^ 1], w, l);
            stage_tile8(vF + (size_t)(b * 64 + (lk0 >> 6) + 1) * 4096, vbuf[cur ^ 1], w, l);
            if (w == 0 && l < 16) g2l16(wE + bL + lk0 + 64 + l * 4, wbuf[cur ^ 1]);
        }

        // QK^T from kbuf[cur]
        f32x4 e4[4];
#pragma unroll
        for (int t = 0; t < 4; ++t) e4[t] = (f32x4){0.f, 0.f, 0.f, 0.f};
        PRIO(1);
#pragma unroll
        for (int t = 0; t < 4; ++t) {
            bf16x8 kf0 = *(const bf16x8*)&kbuf[cur][swz(16 * t + cl, 8 * g)];
            e4[t] = __builtin_amdgcn_mfma_f32_16x16x32_bf16(kf0, qf0, e4[t], 0, 0, 0);
            bf16x8 kf1 = *(const bf16x8*)&kbuf[cur][swz(16 * t + cl, 32 + 8 * g)];
            e4[t] = __builtin_amdgcn_mfma_f32_16x16x32_bf16(kf1, qf1, e4[t], 0, 0, 0);
        }
        PRIO(0);

        float p[4][4];
#pragma unroll
        for (int t = 0; t < 4; ++t) {
            float4 wv = *(const float4*)&wbuf[cur][16 * t + 4 * g];
            p[t][0] = EXP2F(fmaf(e4[t][0], QS2, ls2 + wv.x));
            p[t][1] = EXP2F(fmaf(e4[t][1], QS2, ls2 + wv.y));
            p[t][2] = EXP2F(fmaf(e4[t][2], QS2, ls2 + wv.z));
            p[t][3] = EXP2F(fmaf(e4[t][3], QS2, ls2 + wv.w));
        }

        // PV: A = V fragment (two 4-reg halves), B = P (lane-local)
        bf16x8 pb[2];
#pragma unroll
        for (int s = 0; s < 2; ++s)
#pragma unroll
            for (int j = 0; j < 8; ++j)
                pb[s][j] = (bf16)p[2 * s + (j >> 2)][j & 3];
        PRIO(1);
#pragma unroll
        for (int s = 0; s < 2; ++s) {
            bf16x8 vf4[4];
#pragma unroll
            for (int mt = 0; mt < 4; ++mt)
                vf4[mt] = *(const bf16x8*)&vbuf[cur][((s * 4 + mt) * 64 + l) * 8];
#pragma unroll
            for (int mt = 0; mt < 4; ++mt)
                o4[mt] = __builtin_amdgcn_mfma_f32_16x16x32_bf16(
                    vf4[mt], pb[s], o4[mt], 0, 0, 0);
        }
        PRIO(0);

        // attnT stores LAST: the 16 newest vmem ops
#pragma unroll
        for (int t = 0; t < 4; ++t)
#pragma unroll
            for (int r = 0; r < 4; ++r) {
                int lkg = lk0 + 16 * t + 4 * g + r;
                attnT[(bL + lkg) * LLEN + lq0 + strip + cl] = p[t][r];
            }

        if (it < TPE - 1) {
            WAITVM16;   // retires K/V/wE prefetch; stores stay in flight
            WAITLGKM0;
            BAR();
        }
    }

    // merge partial PV into out
    if (use_part) {
        float* dst = pout + (size_t)chunk * ((size_t)BB * CCH * LLEN);
#pragma unroll
        for (int mt = 0; mt < 4; ++mt)
#pragma unroll
            for (int r = 0; r < 4; ++r) {
                int c = 16 * mt + 4 * g + r;
                dst[obase + (size_t)c * LLEN + lq0 + strip + cl] = o4[mt][r];
            }
    } else {
#pragma unroll
        for (int mt = 0; mt < 4; ++mt)
#pragma unroll
            for (int r = 0; r < 4; ++r) {
                int c = 16 * mt + 4 * g + r;
                atomicAdd(&outp[obase + (size_t)c * LLEN + lq0 + strip + cl], o4[mt][r]);
            }
    }
}

// ---------------- out reduce: out = sum of 4 partials ----------------
__global__ __launch_bounds__(NTB) void out_reduce(
    const float* __restrict__ pout, float* __restrict__ outp)
{
    const size_t S = (size_t)BB * CCH * LLEN;
    size_t i = ((size_t)blockIdx.x * NTB + threadIdx.x) * 4;
    float4 a = *(const float4*)&pout[i];
    float4 b = *(const float4*)&pout[S + i];
    float4 c = *(const float4*)&pout[2 * S + i];
    float4 d = *(const float4*)&pout[3 * S + i];
    float4 o;
    o.x = (a.x + b.x) + (c.x + d.x);
    o.y = (a.y + b.y) + (c.y + d.y);
    o.z = (a.z + b.z) + (c.z + d.z);
    o.w = (a.w + b.w) + (c.w + d.w);
    *(float4*)&outp[i] = o;
}

extern "C" void kernel_launch(void* const* d_in, const int* in_sizes, int n_in,
                              void* d_out, int out_size, void* d_ws, size_t ws_size,
                              hipStream_t stream) {
    const float* qg = (const float*)d_in[0];
    const float* kg = (const float*)d_in[1];
    const float* vg = (const float*)d_in[2];
    const float* mg = (const float*)d_in[3];
    float* outp = (float*)d_out;
    float* attnT = outp + (size_t)BB * CCH * LLEN;

    char* ws = (char*)d_ws;
    bf16* qT = (bf16*)ws;                                   // 2 MB
    bf16* kT = (bf16*)(ws + (2u << 20));                    // 2 MB
    bf16* vF = (bf16*)(ws + (4u << 20));                    // 2 MB
    float* wS = (float*)(ws + (6u << 20));                  // 64 KB
    float* wE = (float*)(ws + (6u << 20) + (64u << 10));    // 64 KB
    float* sums = (float*)(ws + (6u << 20) + (128u << 10)); // 512 KB
    float* pout = (float*)(ws + (7u << 20));                // 16 MB (4 partials)

    const int use_part = (ws_size >= (size_t)(24u << 20)) ? 1 : 0;

    prep_all<<<772, NTB, 0, stream>>>(qg, kg, vg, mg, qT, kT, vF, wS, wE);
    attn_stats<<<BB * (LLEN / TQ) * NCHUNK, NTB, 0, stream>>>(qT, kT, wS, sums, outp,
                                                              use_part ? 0 : 1);
    attn_emit<<<BB * (LLEN / TQE) * NCHE, NTE, 0, stream>>>(qT, kT, vF, wE, sums, outp,
                                                            pout, use_part, attnT);
    if (use_part)
        out_reduce<<<(BB * CCH * LLEN) / (NTB * 4), NTB, 0, stream>>>(pout, outp);
}

// Round 15
// 92.575 us; speedup vs baseline: 1.0098x; 1.0098x over previous
//
#include <hip/hip_runtime.h>
#include <stdint.h>

#define BB 4
#define CCH 64
#define LLEN 4096
#define QS2 0.18033688011112042f   // 0.125 * log2(e)
#define TQ 64
#define TK 64
#define NCHUNK 8
#define TPC 8
#define NTB 256
// emit geometry: 128-lq blocks, 8 waves, 4 chunks of 1024 lk
#define TQE 128
#define NTE 512
#define NCHE 4
#define TPE 16

typedef __bf16 bf16;
typedef bf16 bf16x4 __attribute__((ext_vector_type(4)));
typedef bf16 bf16x8 __attribute__((ext_vector_type(8)));
typedef float f32x4 __attribute__((ext_vector_type(4)));

#define EXP2F(x) __builtin_amdgcn_exp2f(x)
#define LOG2F(x) __builtin_amdgcn_logf(x)

// swizzled element index into a [rows][64 cols] bf16 tile (128B rows)
__device__ __forceinline__ int swz(int row, int col) {
    return row * 64 + (col ^ ((row & 7) << 3));
}

__device__ __forceinline__ void g2l16(const void* g, void* l) {
    __builtin_amdgcn_global_load_lds(
        (const __attribute__((address_space(1))) void*)g,
        (__attribute__((address_space(3))) void*)l, 16, 0, 0);
}

#define WAITVM0 asm volatile("s_waitcnt vmcnt(0)" ::: "memory")
#define WAITVM16 asm volatile("s_waitcnt vmcnt(16)" ::: "memory")
#define WAITLGKM0 asm volatile("s_waitcnt lgkmcnt(0)" ::: "memory")
#define BAR() __builtin_amdgcn_s_barrier()
#define PRIO(n) __builtin_amdgcn_s_setprio(n)

// copy contiguous region global->LDS: 2 g2l16 per wave (4 waves: 8KB, 8 waves: 16KB)
__device__ __forceinline__ void stage_rows(const bf16* src, bf16* dst, int w, int l) {
#pragma unroll
    for (int i = 0; i < 2; ++i) {
        int ci = w * 2 + i;
        g2l16(src + ci * 512 + l * 8, dst + ci * 512);
    }
}
// copy one 8KB contiguous tile with 8 waves (1 g2l16 per wave)
__device__ __forceinline__ void stage_tile8(const bf16* src, bf16* dst, int w, int l) {
    g2l16(src + w * 512 + l * 8, dst + w * 512);
}

// ---------------- prep (merged): Q,K transpose+swizzle | V pack | mask ----------------
__global__ __launch_bounds__(NTB) void prep_all(
    const float* __restrict__ qg, const float* __restrict__ kg,
    const float* __restrict__ vg, const float* __restrict__ mg,
    bf16* __restrict__ qT, bf16* __restrict__ kT,
    bf16* __restrict__ vF, float* __restrict__ wS, float* __restrict__ wE)
{
    const int tid = threadIdx.x;
    if (blockIdx.x < 512) {
        __shared__ float t[64][65];
        const int isK = blockIdx.x >> 8;
        const int idx = blockIdx.x & 255;
        const int b = idx >> 6;
        const int lt = idx & 63;
        const float* src = (isK ? kg : qg) + (size_t)b * CCH * LLEN + lt * 64;
        bf16* dst = (isK ? kT : qT) + ((size_t)b * LLEN + lt * 64) * 64;

        int c = tid >> 2, x0 = (tid & 3) * 16;
#pragma unroll
        for (int j = 0; j < 4; ++j) {
            float4 f = *(const float4*)&src[(size_t)c * LLEN + x0 + j * 4];
            t[c][x0 + j * 4 + 0] = f.x;
            t[c][x0 + j * 4 + 1] = f.y;
            t[c][x0 + j * 4 + 2] = f.z;
            t[c][x0 + j * 4 + 3] = f.w;
        }
        __syncthreads();
        int lk = tid >> 2;
        int g0 = (tid & 3) * 2;
#pragma unroll
        for (int gi = 0; gi < 2; ++gi) {
            int gg = g0 + gi;
            bf16x8 v;
#pragma unroll
            for (int j = 0; j < 8; ++j) v[j] = (bf16)t[gg * 8 + j][lk];
            *(bf16x8*)&dst[lk * 64 + ((gg ^ (lk & 7)) * 8)] = v;
        }
    } else if (blockIdx.x < 768) {
        // V -> PV-fragment-packed: unit ((b*64+tile)*8 + s*4 + mt)*64 + 16*g + cl
        const int row = blockIdx.x - 512;  // b*64 + c
        const int b = row >> 6;
        const int c = row & 63;
        const int mt = c >> 4, cl = c & 15;
        const size_t base = (size_t)row * LLEN;
        const int x0 = tid * 16;
        const int tile = x0 >> 6;
        float f[16];
#pragma unroll
        for (int j = 0; j < 4; ++j) {
            float4 v4 = *(const float4*)&vg[base + x0 + j * 4];
            f[j * 4 + 0] = v4.x; f[j * 4 + 1] = v4.y;
            f[j * 4 + 2] = v4.z; f[j * 4 + 3] = v4.w;
        }
        bf16* vFb = vF + (size_t)(b * 64 + tile) * 4096;
#pragma unroll
        for (int k2 = 0; k2 < 4; ++k2) {
            int rem = (x0 & 63) + 4 * k2;
            int s = rem >> 5, hl = (rem >> 4) & 1, g = (rem >> 2) & 3;
            bf16x4 hv = {(bf16)f[4 * k2 + 0], (bf16)f[4 * k2 + 1],
                         (bf16)f[4 * k2 + 2], (bf16)f[4 * k2 + 3]};
            *(bf16x4*)&vFb[(size_t)(((s * 4 + mt) * 64 + 16 * g + cl) * 8 + hl * 4)] = hv;
        }
    } else {
        const int b = blockIdx.x - 768;
        int x0 = tid * 16;
#pragma unroll
        for (int j = 0; j < 16; ++j) {
            float m = mg[(size_t)b * LLEN + x0 + j];
            float w = m + 1e-6f;
            wS[(size_t)b * LLEN + x0 + j] = LOG2F(w);       // log2(mask + 1e-6)
            wE[(size_t)b * LLEN + x0 + j] = LOG2F(w * m);   // + log2(mask); m=0 -> -inf
        }
    }
}

// ---------------- stats: lk-split waves; per-chunk row sums; zero out ----------------
__global__ __launch_bounds__(NTB) void attn_stats(
    const bf16* __restrict__ qT, const bf16* __restrict__ kT,
    const float* __restrict__ wS, float* __restrict__ sums,
    float* __restrict__ outp)
{
    __shared__ __align__(16) bf16 kbuf[2][TK * CCH];
    __shared__ __align__(16) float wbuf[2][TK];
    __shared__ float red[4][TQ];

    const int tid = threadIdx.x;
    const int l = tid & 63;
    const int w = tid >> 6;          // wave owns lk slice [16w, 16w+16)
    const int g = l >> 4;
    const int cl = l & 15;

    const int idx = blockIdx.x;
    const int chunk = idx & 7;
    const int lqt = (idx >> 3) & 63;
    const int b = idx >> 9;
    const int lq0 = lqt * TQ;
    const size_t bL = (size_t)b * LLEN;

    // zero out region (exactly 2 floats per thread across the grid)
    {
        size_t o = ((size_t)idx * NTB + tid) * 2;
        *(float2*)&outp[o] = make_float2(0.f, 0.f);
    }

    // prologue: Q -> kbuf[1] (transient), K(tile0) -> kbuf[0], wS0 -> wbuf[0]
    stage_rows(qT + (bL + lq0) * 64, kbuf[1], w, l);
    stage_rows(kT + (bL + chunk * 512) * 64, kbuf[0], w, l);
    if (w == 0 && l < 16) g2l16(wS + bL + chunk * 512 + l * 4, wbuf[0]);
    WAITVM0;
    BAR();
    // Q fragments for ALL 4 strips (held in registers; kbuf[1] is then reusable)
    bf16x8 qf[4][2];
#pragma unroll
    for (int strip = 0; strip < 4; ++strip) {
        qf[strip][0] = *(const bf16x8*)&kbuf[1][swz(strip * 16 + cl, 8 * g)];
        qf[strip][1] = *(const bf16x8*)&kbuf[1][swz(strip * 16 + cl, 32 + 8 * g)];
    }
    WAITLGKM0;
    BAR();

    float sacc[4] = {0.f, 0.f, 0.f, 0.f};
#pragma unroll
    for (int it = 0; it < TPC; ++it) {
        const int kcur = it & 1;
        const int lk0 = chunk * 512 + it * 64;

        if (it < TPC - 1) {
            stage_rows(kT + (bL + lk0 + 64) * 64, kbuf[kcur ^ 1], w, l);
            if (w == 0 && l < 16) g2l16(wS + bL + lk0 + 64 + l * 4, wbuf[kcur ^ 1]);
        }

        // A fragments: this wave's own 16-lk slice (only 2 LDS reads/iter)
        bf16x8 kf0 = *(const bf16x8*)&kbuf[kcur][swz(16 * w + cl, 8 * g)];
        bf16x8 kf1 = *(const bf16x8*)&kbuf[kcur][swz(16 * w + cl, 32 + 8 * g)];
        float4 wv = *(const float4*)&wbuf[kcur][16 * w + 4 * g];

        PRIO(1);
#pragma unroll
        for (int strip = 0; strip < 4; ++strip) {
            f32x4 e = (f32x4){0.f, 0.f, 0.f, 0.f};
            e = __builtin_amdgcn_mfma_f32_16x16x32_bf16(kf0, qf[strip][0], e, 0, 0, 0);
            e = __builtin_amdgcn_mfma_f32_16x16x32_bf16(kf1, qf[strip][1], e, 0, 0, 0);
            sacc[strip] += EXP2F(fmaf(e[0], QS2, wv.x));
            sacc[strip] += EXP2F(fmaf(e[1], QS2, wv.y));
            sacc[strip] += EXP2F(fmaf(e[2], QS2, wv.z));
            sacc[strip] += EXP2F(fmaf(e[3], QS2, wv.w));
        }
        PRIO(0);

        if (it < TPC - 1) {
            WAITVM0;
            WAITLGKM0;
            BAR();
        }
    }

    // reduce over g (lanes 16,32 apart hold other lk rows of the slice)
#pragma unroll
    for (int strip = 0; strip < 4; ++strip) {
        sacc[strip] += __shfl_xor(sacc[strip], 16);
        sacc[strip] += __shfl_xor(sacc[strip], 32);
    }
    if (l < 16) {
#pragma unroll
        for (int strip = 0; strip < 4; ++strip) red[w][strip * 16 + l] = sacc[strip];
    }
    __syncthreads();
    if (tid < TQ) {
        float s = red[0][tid] + red[1][tid] + red[2][tid] + red[3][tid];
        sums[(bL + lq0 + tid) * NCHUNK + chunk] = s;
    }
}

// ---------------- emit: 8-wave, 128-lq blocks; QK^T, normalize, attnT, PV ----------------
__global__ __launch_bounds__(NTE, 4) void attn_emit(
    const bf16* __restrict__ qT, const bf16* __restrict__ kT,
    const bf16* __restrict__ vF, const float* __restrict__ wE,
    const float* __restrict__ sums, float* __restrict__ outp,
    float* __restrict__ attnT)
{
    __shared__ __align__(16) bf16 kbuf[2][TK * CCH];   // also Q transient (16KB flat)
    __shared__ __align__(16) bf16 vbuf[2][TK * CCH];
    __shared__ __align__(16) float wbuf[2][TK];

    const int tid = threadIdx.x;
    const int l = tid & 63;
    const int w = tid >> 6;        // 0..7
    const int strip = w * 16;      // lq strip within 128
    const int g = l >> 4;
    const int cl = l & 15;

    const int idx = blockIdx.x;
    const int chunk = idx & (NCHE - 1);
    const int lqt = (idx >> 2) & 31;
    const int b = idx >> 7;
    const int lq0 = lqt * TQE;
    const size_t bL = (size_t)b * LLEN;
    const size_t obase = (size_t)b * CCH * LLEN;
    bf16* kflat = &kbuf[0][0];

    // prologue: Q (16KB) -> kbuf flat
    stage_rows(qT + (bL + lq0) * 64, kflat, w, l);
    float ls2;
    {
        const float4* sp = (const float4*)&sums[(bL + lq0 + strip + cl) * NCHUNK];
        float4 a = sp[0], c4 = sp[1];
        float ssum = ((a.x + a.y) + (a.z + a.w)) + ((c4.x + c4.y) + (c4.z + c4.w));
        ls2 = -LOG2F(ssum);  // p = exp2(e*QS2 + ls2 + l2wE)
    }
    WAITVM0;
    BAR();
    bf16x8 qf0 = *(const bf16x8*)&kflat[swz(strip + cl, 8 * g)];
    bf16x8 qf1 = *(const bf16x8*)&kflat[swz(strip + cl, 32 + 8 * g)];
    WAITLGKM0;
    BAR();

    // stage tile 0
    {
        const int lk0 = chunk * (TPE * TK);
        stage_tile8(kT + (bL + lk0) * 64, kbuf[0], w, l);
        stage_tile8(vF + (size_t)(b * 64 + (lk0 >> 6)) * 4096, vbuf[0], w, l);
        if (w == 0 && l < 16) g2l16(wE + bL + lk0 + l * 4, wbuf[0]);
    }
    WAITVM0;
    BAR();

    f32x4 o4[4];
#pragma unroll
    for (int t = 0; t < 4; ++t) o4[t] = (f32x4){0.f, 0.f, 0.f, 0.f};

#pragma unroll
    for (int it = 0; it < TPE; ++it) {
        const int cur = it & 1;
        const int lk0 = chunk * (TPE * TK) + it * 64;

        if (it < TPE - 1) {
            stage_tile8(kT + (bL + lk0 + 64) * 64, kbuf[cur ^ 1], w, l);
            stage_tile8(vF + (size_t)(b * 64 + (lk0 >> 6) + 1) * 4096, vbuf[cur ^ 1], w, l);
            if (w == 0 && l < 16) g2l16(wE + bL + lk0 + 64 + l * 4, wbuf[cur ^ 1]);
        }

        // QK^T from kbuf[cur]
        f32x4 e4[4];
#pragma unroll
        for (int t = 0; t < 4; ++t) e4[t] = (f32x4){0.f, 0.f, 0.f, 0.f};
        PRIO(1);
#pragma unroll
        for (int t = 0; t < 4; ++t) {
            bf16x8 kf0 = *(const bf16x8*)&kbuf[cur][swz(16 * t + cl, 8 * g)];
            e4[t] = __builtin_amdgcn_mfma_f32_16x16x32_bf16(kf0, qf0, e4[t], 0, 0, 0);
            bf16x8 kf1 = *(const bf16x8*)&kbuf[cur][swz(16 * t + cl, 32 + 8 * g)];
            e4[t] = __builtin_amdgcn_mfma_f32_16x16x32_bf16(kf1, qf1, e4[t], 0, 0, 0);
        }
        PRIO(0);

        float p[4][4];
#pragma unroll
        for (int t = 0; t < 4; ++t) {
            float4 wv = *(const float4*)&wbuf[cur][16 * t + 4 * g];
            p[t][0] = EXP2F(fmaf(e4[t][0], QS2, ls2 + wv.x));
            p[t][1] = EXP2F(fmaf(e4[t][1], QS2, ls2 + wv.y));
            p[t][2] = EXP2F(fmaf(e4[t][2], QS2, ls2 + wv.z));
            p[t][3] = EXP2F(fmaf(e4[t][3], QS2, ls2 + wv.w));
        }

        // PV: A = V fragment (two 4-reg halves), B = P (lane-local)
        bf16x8 pb[2];
#pragma unroll
        for (int s = 0; s < 2; ++s)
#pragma unroll
            for (int j = 0; j < 8; ++j)
                pb[s][j] = (bf16)p[2 * s + (j >> 2)][j & 3];
        PRIO(1);
#pragma unroll
        for (int s = 0; s < 2; ++s) {
            bf16x8 vf4[4];
#pragma unroll
            for (int mt = 0; mt < 4; ++mt)
                vf4[mt] = *(const bf16x8*)&vbuf[cur][((s * 4 + mt) * 64 + l) * 8];
#pragma unroll
            for (int mt = 0; mt < 4; ++mt)
                o4[mt] = __builtin_amdgcn_mfma_f32_16x16x32_bf16(
                    vf4[mt], pb[s], o4[mt], 0, 0, 0);
        }
        PRIO(0);

        // attnT stores LAST: the 16 newest vmem ops
#pragma unroll
        for (int t = 0; t < 4; ++t)
#pragma unroll
            for (int r = 0; r < 4; ++r) {
                int lkg = lk0 + 16 * t + 4 * g + r;
                attnT[(bL + lkg) * LLEN + lq0 + strip + cl] = p[t][r];
            }

        if (it < TPE - 1) {
            WAITVM16;   // retires K/V/wE prefetch; stores stay in flight
            WAITLGKM0;
            BAR();
        }
    }

    // merge partial PV into out (NCHE adds per element)
#pragma unroll
    for (int mt = 0; mt < 4; ++mt)
#pragma unroll
        for (int r = 0; r < 4; ++r) {
            int c = 16 * mt + 4 * g + r;
            atomicAdd(&outp[obase + (size_t)c * LLEN + lq0 + strip + cl], o4[mt][r]);
        }
}

extern "C" void kernel_launch(void* const* d_in, const int* in_sizes, int n_in,
                              void* d_out, int out_size, void* d_ws, size_t ws_size,
                              hipStream_t stream) {
    const float* qg = (const float*)d_in[0];
    const float* kg = (const float*)d_in[1];
    const float* vg = (const float*)d_in[2];
    const float* mg = (const float*)d_in[3];
    float* outp = (float*)d_out;
    float* attnT = outp + (size_t)BB * CCH * LLEN;

    char* ws = (char*)d_ws;
    bf16* qT = (bf16*)ws;                                   // 2 MB
    bf16* kT = (bf16*)(ws + (2u << 20));                    // 2 MB
    bf16* vF = (bf16*)(ws + (4u << 20));                    // 2 MB
    float* wS = (float*)(ws + (6u << 20));                  // 64 KB
    float* wE = (float*)(ws + (6u << 20) + (64u << 10));    // 64 KB
    float* sums = (float*)(ws + (6u << 20) + (128u << 10)); // 512 KB

    prep_all<<<772, NTB, 0, stream>>>(qg, kg, vg, mg, qT, kT, vF, wS, wE);
    attn_stats<<<BB * (LLEN / TQ) * NCHUNK, NTB, 0, stream>>>(qT, kT, wS, sums, outp);
    attn_emit<<<BB * (LLEN / TQE) * NCHE, NTE, 0, stream>>>(qT, kT, vF, wE, sums, outp, attnT);
}